// Round 1
// baseline (386.462 us; speedup 1.0000x reference)
//
#include <hip/hip_runtime.h>
#include <stdint.h>

// ============================================================================
// R6: replace the m97-structure 128^2 GEMM (826 TF measured, MfmaUtil 35%)
//     with a phase-split counted-vmcnt GEMM (T2 swizzle + T3/T4 + T5):
//     BM=128, BN=256, BK=64, 8 waves (wave tile 64x64), TRIPLE-buffered LDS
//     (144 KB) so staged writes can never race in-flight ds_reads, and the
//     single s_waitcnt vmcnt(6) per K-tile provably guarantees tile T+1
//     landed (6 loads in flight = this iteration's own stage issues).
//     Geometry chosen for grid quantization: QKV 32x24=768 blocks (3 exact
//     rounds at 1 block/CU), Wo 32x8=256 (1 exact round).
//     cast_all / transpose_v / attn_mfma unchanged from R5.
// Shapes fixed: B=2, S=2048, D=2048, H=16, HD=128, window=512 (runtime-read).
// ws layout (bytes): xb@0 (16M, vtb aliases after QKV gemm) | wqkv@16M (25.2M)
//   wob@41.9M | qb@48M kb@64M vb@80M (16M apart = 8388608 elems) | ab@96M.
// ============================================================================

typedef __attribute__((ext_vector_type(8))) short short8;
typedef __attribute__((ext_vector_type(4))) float f32x4;

#define DEV static __device__ __forceinline__

DEV unsigned short f2bf(float f) {
  unsigned u = __builtin_bit_cast(unsigned, f);
  u += 0x7fffu + ((u >> 16) & 1u);  // RNE
  return (unsigned short)(u >> 16);
}

// async global->LDS, 16B/lane; LDS dest = wave-uniform base + lane*16
DEV void async16(const void* g, void* l) {
  __builtin_amdgcn_global_load_lds(
      (const __attribute__((address_space(1))) unsigned int*)g,
      (__attribute__((address_space(3))) unsigned int*)l, 16, 0, 0);
}

// ---------------------------------------------------------------------------
// Fused fp32 -> bf16 cast for x + Wq + Wk + Wv + Wo. 8 elems/thread.
// ---------------------------------------------------------------------------
__global__ __launch_bounds__(256) void cast_all(
    const float* __restrict__ x, const float* __restrict__ Wq,
    const float* __restrict__ Wk, const float* __restrict__ Wv,
    const float* __restrict__ Wo, unsigned short* __restrict__ xb,
    unsigned short* __restrict__ wqkv, unsigned short* __restrict__ wob) {
  const int bid = blockIdx.x;
  const float* src;
  unsigned short* dst;
  int i;
  if (bid < 4096) {
    src = x; dst = xb; i = bid * 256 + threadIdx.x;
  } else if (bid < 6144) {
    src = Wq; dst = wqkv; i = (bid - 4096) * 256 + threadIdx.x;
  } else if (bid < 8192) {
    src = Wk; dst = wqkv + 4194304; i = (bid - 6144) * 256 + threadIdx.x;
  } else if (bid < 10240) {
    src = Wv; dst = wqkv + 8388608; i = (bid - 8192) * 256 + threadIdx.x;
  } else {
    src = Wo; dst = wob; i = (bid - 10240) * 256 + threadIdx.x;
  }
  const float4* s4 = (const float4*)src;
  float4 a = s4[2 * (size_t)i], b = s4[2 * (size_t)i + 1];
  short8 o;
  o[0] = (short)f2bf(a.x); o[1] = (short)f2bf(a.y);
  o[2] = (short)f2bf(a.z); o[3] = (short)f2bf(a.w);
  o[4] = (short)f2bf(b.x); o[5] = (short)f2bf(b.y);
  o[6] = (short)f2bf(b.z); o[7] = (short)f2bf(b.w);
  *(short8*)(dst + 8 * (size_t)i) = o;
}

// ---------------------------------------------------------------------------
// C = A[M,K] * B[NT,K]^T, k-contiguous bf16. M=4096, K=2048 fixed.
// BM=128 / BN=256 / BK=64; 512 threads = 8 waves, wave tile 64x64.
// Triple-buffered LDS; per K-tile: 4 phases {barrier; 8 MFMA} with 2
// global_load_lds stage-issues between phases and one counted vmcnt(6).
// Swizzle: 16B chunk c of row r lives at LDS chunk c^(r&7); staging keeps LDS
// linear and pre-inverse-swizzles the GLOBAL source (rule #21, m173/m201).
// Grid: flat, XCD-bijective swizzle (grid % 8 == 0 for both call sites),
// decode bx = swz & 31 (M/128 = 32 for both GEMMs), by = swz >> 5.
// nb = global col >> 11 selects output buffer (QKV fusion), as before.
// ---------------------------------------------------------------------------
constexpr int GK = 2048, GN = 2048;

#define GEMM_PHASE(ni_)                                                     \
  __builtin_amdgcn_s_setprio(1);                                            \
  {                                                                         \
    _Pragma("unroll") for (int mi = 0; mi < 4; ++mi) {                      \
      acc[mi][ni_] = __builtin_amdgcn_mfma_f32_16x16x32_bf16(               \
          af[mi][0], bfr[ni_][0], acc[mi][ni_], 0, 0, 0);                   \
      acc[mi][ni_] = __builtin_amdgcn_mfma_f32_16x16x32_bf16(               \
          af[mi][1], bfr[ni_][1], acc[mi][ni_], 0, 0, 0);                   \
    }                                                                       \
  }                                                                         \
  __builtin_amdgcn_s_setprio(0);

template <bool STORE_BF16>
__global__ __launch_bounds__(512, 2) void gemm_bt8(
    const unsigned short* __restrict__ A, const unsigned short* __restrict__ B,
    void* __restrict__ Cout, size_t obuf_stride) {
  __shared__ short As[3][128 * 64];  // 3 x 16 KB
  __shared__ short Bs[3][256 * 64];  // 3 x 32 KB   (total 144 KB)

  const int t = threadIdx.x;
  const int lane = t & 63;
  const int quad = lane >> 4, l15 = lane & 15, l7 = l15 & 7;
  const int w = t >> 6, wm = w >> 2, wn = w & 3;

  // XCD-bijective block swizzle: contiguous swz chunk per XCD.
  const int nwg = (int)gridDim.x;
  const int cpx = nwg >> 3;
  const int swz = ((int)blockIdx.x & 7) * cpx + ((int)blockIdx.x >> 3);
  const int bx = swz & 31;        // M tile (M = 4096 -> 32 tiles of 128)
  const int by = swz >> 5;        // N tile of 256
  const int row0 = bx * 128;
  const int col0g = by * 256;
  const int nb = col0g >> 11, col0 = col0g & 2047;

  // ---- staging source (pre-inverse-swizzled chunk; r&7 == (t>>3)&7 for all
  //      sub-rows since row offsets are multiples of 64) ----
  const int rsub = t >> 3;                       // 0..63
  const int cg8 = ((t & 7) ^ (rsub & 7)) << 3;   // source elem offset
  const unsigned short* Ag = A + (size_t)(row0 + rsub) * GK + cg8;
  const unsigned short* Bg = B + (size_t)(col0g + rsub) * GK + cg8;
  const int loff = rsub * 128 + (t & 7) * 16;    // linear LDS byte offset

  auto stageA = [&](int buf, int kt) {
    async16(Ag + (size_t)kt * 64, (char*)As[buf] + loff);
    async16(Ag + 64 * (size_t)GK + (size_t)kt * 64,
            (char*)As[buf] + 8192 + loff);
  };
  auto stageB01 = [&](int buf, int kt) {
    async16(Bg + (size_t)kt * 64, (char*)Bs[buf] + loff);
    async16(Bg + 64 * (size_t)GK + (size_t)kt * 64,
            (char*)Bs[buf] + 8192 + loff);
  };
  auto stageB23 = [&](int buf, int kt) {
    async16(Bg + 128 * (size_t)GK + (size_t)kt * 64,
            (char*)Bs[buf] + 16384 + loff);
    async16(Bg + 192 * (size_t)GK + (size_t)kt * 64,
            (char*)Bs[buf] + 24576 + loff);
  };

  // ---- fragment read offsets (elements), swizzled chunk = (kc*4+quad)^l7 ----
  int aoff[4][2], boff[4][2];
#pragma unroll
  for (int mi = 0; mi < 4; ++mi)
#pragma unroll
    for (int kc = 0; kc < 2; ++kc)
      aoff[mi][kc] =
          (wm * 64 + mi * 16 + l15) * 64 + (((kc * 4 + quad) ^ l7) << 3);
#pragma unroll
  for (int ni = 0; ni < 4; ++ni)
#pragma unroll
    for (int kc = 0; kc < 2; ++kc)
      boff[ni][kc] =
          (wn * 64 + ni * 16 + l15) * 64 + (((kc * 4 + quad) ^ l7) << 3);

  f32x4 acc[4][4] = {};
  constexpr int NT = GK / 64;  // 32

  // ---- prologue: tile0 -> buf0, tile1 -> buf1 (6 loads each) ----
  stageA(0, 0); stageB01(0, 0); stageB23(0, 0);
  stageA(1, 1); stageB01(1, 1); stageB23(1, 1);
  __asm__ __volatile__("s_waitcnt vmcnt(6)" ::: "memory");  // tile0 landed
  __builtin_amdgcn_s_barrier();

  int bufR = 0;
  for (int T = 0; T < NT; ++T) {
    const short* ab = As[bufR];
    const short* bb = Bs[bufR];
    int bufW = bufR + 2; if (bufW >= 3) bufW -= 3;  // tile T+2's buffer

    // all 16 fragment reads issued up front; compiler emits counted lgkmcnt
    // so MFMA ni=0 starts after the first 10 while bfr[1..3] stay in flight.
    short8 af[4][2], bfr[4][2];
#pragma unroll
    for (int mi = 0; mi < 4; ++mi) {
      af[mi][0] = *(const short8*)(ab + aoff[mi][0]);
      af[mi][1] = *(const short8*)(ab + aoff[mi][1]);
    }
#pragma unroll
    for (int ni = 0; ni < 4; ++ni) {
      bfr[ni][0] = *(const short8*)(bb + boff[ni][0]);
      bfr[ni][1] = *(const short8*)(bb + boff[ni][1]);
    }
    __builtin_amdgcn_s_barrier();
    GEMM_PHASE(0)

    if (T + 2 < NT) stageA(bufW, T + 2);
    __builtin_amdgcn_s_barrier();
    GEMM_PHASE(1)

    if (T + 2 < NT) stageB01(bufW, T + 2);
    __builtin_amdgcn_s_barrier();
    GEMM_PHASE(2)

    if (T + 2 < NT) stageB23(bufW, T + 2);
    // counted wait: allow this iteration's own 6 stage-loads in flight;
    // everything older (= all of tile T+1) must have landed.
    if (T < NT - 2) {
      __asm__ __volatile__("s_waitcnt vmcnt(6)" ::: "memory");
    } else if (T == NT - 2) {
      __asm__ __volatile__("s_waitcnt vmcnt(0)" ::: "memory");
    }
    __builtin_amdgcn_s_barrier();
    GEMM_PHASE(3)

    bufR = bufR + 1 == 3 ? 0 : bufR + 1;
  }

  // ---- epilogue ----
#pragma unroll
  for (int mi = 0; mi < 4; ++mi)
#pragma unroll
    for (int ni = 0; ni < 4; ++ni)
#pragma unroll
      for (int r = 0; r < 4; ++r) {
        int row = row0 + wm * 64 + mi * 16 + quad * 4 + r;
        int col = col0 + wn * 64 + ni * 16 + l15;
        if (STORE_BF16)
          ((unsigned short*)Cout)[nb * obuf_stride + (size_t)row * GN + col] =
              f2bf(acc[mi][ni][r]);
        else
          ((float*)Cout)[nb * obuf_stride + (size_t)row * GN + col] =
              acc[mi][ni][r];
      }
}

// ---------------------------------------------------------------------------
// V transpose: vb[b*S+s][d] -> vtb[(b*H + d>>7)*128 + (d&127)][s]
// ---------------------------------------------------------------------------
__global__ __launch_bounds__(256) void transpose_v(
    const unsigned short* __restrict__ vb, unsigned short* __restrict__ vtb) {
  __shared__ unsigned short tile[64][72];
  const int s0 = blockIdx.x * 64, d0 = blockIdx.y * 64, b = blockIdx.z;
  const int tid = threadIdx.x;
  const int c8 = tid & 7;
#pragma unroll
  for (int i = 0; i < 2; ++i) {
    int row = i * 32 + (tid >> 3);
    uint4 v = *(const uint4*)(vb + (size_t)(b * 2048 + s0 + row) * 2048 + d0 + c8 * 8);
    *(uint4*)&tile[row][c8 * 8] = v;
  }
  __syncthreads();
#pragma unroll
  for (int i = 0; i < 2; ++i) {
    int dr = i * 32 + (tid >> 3);
    short8 sv;
#pragma unroll
    for (int j = 0; j < 8; ++j) sv[j] = (short)tile[c8 * 8 + j][dr];
    int d = d0 + dr;
    int h = d >> 7, hd = d & 127;
    *(short8*)(vtb + ((size_t)(b * 16 + h) * 128 + hd) * 2048 + s0 + c8 * 8) = sv;
  }
}

// ---------------------------------------------------------------------------
// MFMA flash attention (R2 structure, measured 68 µs). Block = 64 q-rows of
// one (b,h); 4 waves, wave owns 16 q rows. Grid is FLAT 1024 with XCD-aware
// mapping: f = qt*32 + g (g = b*16+h), so all 32 q-tiles of a (b,h) group
// land on XCD g%8 (4 groups/XCD -> ~4MB K+V resident per XCD L2).
// ---------------------------------------------------------------------------
__global__ __launch_bounds__(256, 3) void attn_mfma(
    const unsigned short* __restrict__ Qm, const unsigned short* __restrict__ Km,
    const unsigned short* __restrict__ Vt, unsigned short* __restrict__ Om,
    const int* __restrict__ amask, const int* __restrict__ winp) {
  constexpr int S = 2048, D = 2048, HD = 128;
  const float SCALE = 0.08838834764831845f;  // 1/sqrt(128)

  __shared__ short Ks[64 * 128];   // K[key][d], chunk-swizzled (16 chunks/row)
  __shared__ short Vts[128 * 64];  // Vt[d][key], chunk-swizzled (8 chunks/row)
  __shared__ short Ps[4][16 * 64]; // per-wave P[q][key], swizzled (8 chunks/row)

  const int t = threadIdx.x, w = t >> 6, lane = t & 63;
  const int quad = lane >> 4, l15 = lane & 15;
  const int l7 = l15 & 7;
  // XCD-aware decode: f = qt*32 + (b*16+h)
  const int f = blockIdx.x;
  const int qt = f >> 5, g = f & 31;
  const int h = g & 15, b = g >> 4;
  const int qi0 = qt * 64;
  const int win = winp[0];

  // Q A-frags: A[m=l15][k=quad*8+j], 4 k-chunks of 32
  short8 qf[4];
  {
    const unsigned short* qp =
        Qm + (size_t)(b * S + qi0 + w * 16 + l15) * D + h * HD + quad * 8;
#pragma unroll
    for (int kc = 0; kc < 4; ++kc) qf[kc] = *(const short8*)(qp + kc * 32);
  }

  f32x4 o[8] = {};              // O[q=quad*4+r][d=ni2*16+l15]
  float m_r[4], l_r[4];
#pragma unroll
  for (int r = 0; r < 4; ++r) { m_r[r] = -1e30f; l_r[r] = 0.f; }

  int lowj = qi0 - win + 1;
  if (lowj < 0) lowj = 0;
  const int jt0 = lowj >> 6;

  const int krow = lane >> 4, kpos = lane & 15;  // K staging
  const int vrow = lane >> 3, vpos = lane & 7;   // Vt staging

  for (int jt = jt0; jt <= qt; ++jt) {
    const int j0 = jt * 64;
    __syncthreads();  // (A) prev tile's LDS reads done
#pragma unroll
    for (int ii = 0; ii < 4; ++ii) {
      int row = ii * 16 + w * 4 + krow;
      int c = kpos ^ (row & 7);
      async16(Km + (size_t)(b * S + j0 + row) * D + h * HD + c * 8,
              (char*)Ks + (ii * 16 + w * 4) * 256);
    }
#pragma unroll
    for (int ii = 0; ii < 4; ++ii) {
      int row = ii * 32 + w * 8 + vrow;
      int c = vpos ^ (row & 7);
      async16(Vt + ((size_t)(b * 16 + h) * 128 + row) * S + j0 + c * 8,
              (char*)Vts + (ii * 32 + w * 8) * 128);
    }
    __syncthreads();  // (B) K, Vt visible

    // ---- QK^T: S[q=quad*4+r][key=ni*16+l15] ----
    f32x4 sS[4];
#pragma unroll
    for (int ni = 0; ni < 4; ++ni) {
      f32x4 acc = {0.f, 0.f, 0.f, 0.f};
#pragma unroll
      for (int kc = 0; kc < 4; ++kc) {
        int pos = (kc * 4 + quad) ^ l7;
        short8 bk = *(const short8*)&Ks[(ni * 16 + l15) * 128 + pos * 8];
        acc = __builtin_amdgcn_mfma_f32_16x16x32_bf16(qf[kc], bk, acc, 0, 0, 0);
      }
      sS[ni] = acc;
    }

    // ---- mask + online softmax (quad-local rows) ----
    float sv[4][4];
    int amv[4];
#pragma unroll
    for (int ni = 0; ni < 4; ++ni) amv[ni] = amask[b * S + j0 + ni * 16 + l15];
#pragma unroll
    for (int ni = 0; ni < 4; ++ni)
#pragma unroll
      for (int r = 0; r < 4; ++r) {
        int gi = qi0 + w * 16 + quad * 4 + r;
        int gj = j0 + ni * 16 + l15;
        bool ok = (gj <= gi) && (gj >= gi - win + 1) && (amv[ni] != 0);
        sv[ni][r] = ok ? sS[ni][r] * SCALE : -1e30f;
      }
    float alpha[4], mnew[4];
#pragma unroll
    for (int r = 0; r < 4; ++r) {
      float mx = fmaxf(fmaxf(sv[0][r], sv[1][r]), fmaxf(sv[2][r], sv[3][r]));
      mx = fmaxf(mx, __shfl_xor(mx, 1));
      mx = fmaxf(mx, __shfl_xor(mx, 2));
      mx = fmaxf(mx, __shfl_xor(mx, 4));
      mx = fmaxf(mx, __shfl_xor(mx, 8));
      float mn = fmaxf(m_r[r], mx);
      alpha[r] = __expf(m_r[r] - mn);
      m_r[r] = mn;
      mnew[r] = mn;
    }
    float rs[4] = {0.f, 0.f, 0.f, 0.f};
#pragma unroll
    for (int ni = 0; ni < 4; ++ni)
#pragma unroll
      for (int r = 0; r < 4; ++r) {
        float p = (sv[ni][r] > -1e29f) ? __expf(sv[ni][r] - mnew[r]) : 0.f;
        sv[ni][r] = p;
        rs[r] += p;
      }
#pragma unroll
    for (int r = 0; r < 4; ++r) {
      float s = rs[r];
      s += __shfl_xor(s, 1);
      s += __shfl_xor(s, 2);
      s += __shfl_xor(s, 4);
      s += __shfl_xor(s, 8);
      l_r[r] = l_r[r] * alpha[r] + s;
    }
    // write P (bf16) into this wave's A-layout tile
#pragma unroll
    for (int ni = 0; ni < 4; ++ni)
#pragma unroll
      for (int r = 0; r < 4; ++r) {
        int row = quad * 4 + r;
        int col = ni * 16 + l15;
        int pos = (col >> 3) ^ (row & 7);
        Ps[w][row * 64 + pos * 8 + (col & 7)] = (short)f2bf(sv[ni][r]);
      }
    // rescale O
#pragma unroll
    for (int ni2 = 0; ni2 < 8; ++ni2)
#pragma unroll
      for (int r = 0; r < 4; ++r) o[ni2][r] *= alpha[r];

    // same-wave LDS write->read: drain lgkm, no barrier needed
    __asm__ __volatile__("s_waitcnt lgkmcnt(0)" ::: "memory");

    // ---- PV: O[q][d] += P[q][key] * Vt[d][key]^T ----
    short8 aP[2];
#pragma unroll
    for (int kc2 = 0; kc2 < 2; ++kc2) {
      int pos = (kc2 * 4 + quad) ^ l7;
      aP[kc2] = *(const short8*)&Ps[w][l15 * 64 + pos * 8];
    }
#pragma unroll
    for (int ni2 = 0; ni2 < 8; ++ni2) {
#pragma unroll
      for (int kc2 = 0; kc2 < 2; ++kc2) {
        int pos = (kc2 * 4 + quad) ^ l7;
        short8 bv = *(const short8*)&Vts[(ni2 * 16 + l15) * 64 + pos * 8];
        o[ni2] = __builtin_amdgcn_mfma_f32_16x16x32_bf16(aP[kc2], bv, o[ni2], 0, 0, 0);
      }
    }
  }

  // epilogue: O / l
  float inv[4];
#pragma unroll
  for (int r = 0; r < 4; ++r) inv[r] = 1.f / l_r[r];
#pragma unroll
  for (int ni2 = 0; ni2 < 8; ++ni2)
#pragma unroll
    for (int r = 0; r < 4; ++r) {
      int row = qi0 + w * 16 + quad * 4 + r;
      Om[(size_t)(b * S + row) * D + h * HD + ni2 * 16 + l15] =
          f2bf(o[ni2][r] * inv[r]);
    }
}

// ---------------------------------------------------------------------------
extern "C" void kernel_launch(void* const* d_in, const int* in_sizes, int n_in,
                              void* d_out, int out_size, void* d_ws,
                              size_t ws_size, hipStream_t stream) {
  (void)in_sizes; (void)n_in; (void)out_size; (void)ws_size;
  const float* x  = (const float*)d_in[0];
  const float* Wq = (const float*)d_in[1];
  const float* Wk = (const float*)d_in[2];
  const float* Wv = (const float*)d_in[3];
  const float* Wo = (const float*)d_in[4];
  const int* am   = (const int*)d_in[5];
  const int* win  = (const int*)d_in[6];
  // d_in[7] sink_tokens: unused (sink mask == causal per reference)

  char* ws = (char*)d_ws;  // needs >= 112 MB
  unsigned short* xb   = (unsigned short*)(ws + 0);
  unsigned short* vtb  = (unsigned short*)(ws + 0);  // aliases xb (dead then)
  unsigned short* wqkv = (unsigned short*)(ws + 16777216);  // [6144,2048]
  unsigned short* wob  = (unsigned short*)(ws + 41943040);
  unsigned short* qb   = (unsigned short*)(ws + 50331648);
  unsigned short* kb   = (unsigned short*)(ws + 67108864);  // qb + 8388608
  unsigned short* vb   = (unsigned short*)(ws + 83886080);  // qb + 2*8388608
  unsigned short* ab   = (unsigned short*)(ws + 100663296);

  cast_all<<<dim3(12288), dim3(256), 0, stream>>>(x, Wq, Wk, Wv, Wo, xb, wqkv, wob);

  // fused QKV: N_total = 6144 -> 768 blocks (3 exact CU rounds);
  // col block >>11 -> {qb, kb, vb}
  gemm_bt8<true><<<dim3(768), dim3(512), 0, stream>>>(xb, wqkv, qb, 8388608);

  transpose_v<<<dim3(32, 32, 2), dim3(256), 0, stream>>>(vb, vtb);

  // flat 1024-block grid, XCD-swizzled (f = qt*32 + b*16 + h)
  attn_mfma<<<dim3(1024), dim3(256), 0, stream>>>(qb, kb, vtb, ab, am, win);

  // Wo GEMM: 32x8 = 256 blocks (1 exact CU round), fp32 out
  gemm_bt8<false><<<dim3(256), dim3(512), 0, stream>>>(ab, wob, d_out, 0);
}

// Round 2
// 378.769 us; speedup vs baseline: 1.0203x; 1.0203x over previous
//
#include <hip/hip_runtime.h>
#include <stdint.h>

// ============================================================================
// R7: faithful m201-style 256x256 8-phase GEMM (wave tile 128x64 = 42.7
//     FLOP/B LDS intensity vs R6's 32), double-buffered 128KB LDS, one
//     16KB half-tile staged per phase, counted vmcnt(4) at phases 4/8 only.
//     R6 post-mortem: swizzle worked (conflicts->0) but 64x64 wave tile was
//     LDS-BW-bound and the all-frags-up-front burst serialized LDS vs MFMA.
//     Stage-region liveness (iter i computes tiles 2i (buf0, ph1-4) and
//     2i+1 (buf1, ph5-8)):
//       ph1: A0(2i+1)  [buf1.A dead since prev ph7]   reads: A(mq0)+B(nq0)
//       ph2: A1(2i+1)                                  reads: B(nq1)
//       ph3: B0(2i+2)  [buf0.B dead since ph2]         reads: A(mq1)
//       ph4: B1(2i+2)  vmcnt(4) -> A(2i+1) landed      reads: none
//       ph5: A0(2i+2)  [buf0.A dead since ph3]         reads: A(mq0)+B(nq0)
//       ph6: A1(2i+2)                                  reads: B(nq1)
//       ph7: B0(2i+3)  [buf1.B dead since ph6]         reads: A(mq1)
//       ph8: B1(2i+3)  vmcnt(4) -> A,B(2i+2) landed    reads: none
//     Prologue: A(0),B(0),B(1) staged (12 loads), vmcnt(4) -> tile0 landed.
//     Last iter (i=15) peeled: only ph1/2 stages (A(31)), vmcnt(0) at ph4.
//     cast_all / transpose_v / attn_mfma unchanged.
// Shapes fixed: B=2, S=2048, D=2048, H=16, HD=128, window=512 (runtime-read).
// ws layout (bytes): xb@0 (16M, vtb aliases after QKV gemm) | wqkv@16M (25.2M)
//   wob@41.9M | qb@48M kb@64M vb@80M (16M apart = 8388608 elems) | ab@96M.
// ============================================================================

typedef __attribute__((ext_vector_type(8))) short short8;
typedef __attribute__((ext_vector_type(4))) float f32x4;

#define DEV static __device__ __forceinline__

DEV unsigned short f2bf(float f) {
  unsigned u = __builtin_bit_cast(unsigned, f);
  u += 0x7fffu + ((u >> 16) & 1u);  // RNE
  return (unsigned short)(u >> 16);
}

// async global->LDS, 16B/lane; LDS dest = wave-uniform base + lane*16
DEV void async16(const void* g, void* l) {
  __builtin_amdgcn_global_load_lds(
      (const __attribute__((address_space(1))) unsigned int*)g,
      (__attribute__((address_space(3))) unsigned int*)l, 16, 0, 0);
}

// ---------------------------------------------------------------------------
// Fused fp32 -> bf16 cast for x + Wq + Wk + Wv + Wo. 8 elems/thread.
// ---------------------------------------------------------------------------
__global__ __launch_bounds__(256) void cast_all(
    const float* __restrict__ x, const float* __restrict__ Wq,
    const float* __restrict__ Wk, const float* __restrict__ Wv,
    const float* __restrict__ Wo, unsigned short* __restrict__ xb,
    unsigned short* __restrict__ wqkv, unsigned short* __restrict__ wob) {
  const int bid = blockIdx.x;
  const float* src;
  unsigned short* dst;
  int i;
  if (bid < 4096) {
    src = x; dst = xb; i = bid * 256 + threadIdx.x;
  } else if (bid < 6144) {
    src = Wq; dst = wqkv; i = (bid - 4096) * 256 + threadIdx.x;
  } else if (bid < 8192) {
    src = Wk; dst = wqkv + 4194304; i = (bid - 6144) * 256 + threadIdx.x;
  } else if (bid < 10240) {
    src = Wv; dst = wqkv + 8388608; i = (bid - 8192) * 256 + threadIdx.x;
  } else {
    src = Wo; dst = wob; i = (bid - 10240) * 256 + threadIdx.x;
  }
  const float4* s4 = (const float4*)src;
  float4 a = s4[2 * (size_t)i], b = s4[2 * (size_t)i + 1];
  short8 o;
  o[0] = (short)f2bf(a.x); o[1] = (short)f2bf(a.y);
  o[2] = (short)f2bf(a.z); o[3] = (short)f2bf(a.w);
  o[4] = (short)f2bf(b.x); o[5] = (short)f2bf(b.y);
  o[6] = (short)f2bf(b.z); o[7] = (short)f2bf(b.w);
  *(short8*)(dst + 8 * (size_t)i) = o;
}

// ---------------------------------------------------------------------------
// C = A[M,K] * B[NT,K]^T, k-contiguous bf16. M=4096, K=2048 fixed.
// BM=BN=256, BK=64; 512 threads = 8 waves (2M x 4N), wave tile 128x64.
// LDS: A 2x32KB + B 2x32KB = 128 KB. Half-tile = 128 rows x 64k = 16 KB,
// staged by 512 threads x 2 x async16. Swizzle: 16B chunk c of row r at
// phys chunk c^(r&7); LDS linear, global source pre-inverse-swizzled.
// Grid flat, XCD-bijective (grid%8==0): bx = swz&15 (M=4096 -> 16 tiles),
// by = swz>>4. nb = global col >> 11 selects output buffer (QKV fusion).
// ---------------------------------------------------------------------------
constexpr int GK = 2048, GN = 2048;

#define MFMA_BF16 __builtin_amdgcn_mfma_f32_16x16x32_bf16

#define STAGE_A(buf, h, kt)                                                  \
  {                                                                          \
    const unsigned short* g_ = Ag + (size_t)((h) * 128) * GK + (kt) * 64;    \
    char* d_ = (char*)As[buf] + (h) * 16384 + loff;                          \
    async16(g_, d_);                                                         \
    async16(g_ + (size_t)64 * GK, d_ + 8192);                                \
  }
#define STAGE_B(buf, h, kt)                                                  \
  {                                                                          \
    const unsigned short* g_ = Bg + (size_t)((h) * 128) * GK + (kt) * 64;    \
    char* d_ = (char*)Bs[buf] + (h) * 16384 + loff;                          \
    async16(g_, d_);                                                         \
    async16(g_ + (size_t)64 * GK, d_ + 8192);                                \
  }

#define READ_A(buf, mq_)                                                     \
  _Pragma("unroll") for (int mi = 0; mi < 4; ++mi)                           \
      _Pragma("unroll") for (int kc = 0; kc < 2; ++kc) afr[mi][kc] =         \
      *(const short8*)(As[buf] + (mq_)*4096 + aoff[mi][kc]);
#define READ_B01(buf)                                                        \
  _Pragma("unroll") for (int ni = 0; ni < 2; ++ni)                           \
      _Pragma("unroll") for (int kc = 0; kc < 2; ++kc) bfr[ni][kc] =         \
      *(const short8*)(Bs[buf] + boff[ni][kc]);
#define READ_B23(buf)                                                        \
  _Pragma("unroll") for (int ni = 2; ni < 4; ++ni)                           \
      _Pragma("unroll") for (int kc = 0; kc < 2; ++kc) bfr[ni][kc] =         \
      *(const short8*)(Bs[buf] + boff[ni][kc]);

#define PH_MFMA(mq_, nq_)                                                    \
  __builtin_amdgcn_s_setprio(1);                                             \
  _Pragma("unroll") for (int mi = 0; mi < 4; ++mi)                           \
      _Pragma("unroll") for (int ni = 0; ni < 2; ++ni) {                     \
    acc[(mq_)*4 + mi][(nq_)*2 + ni] =                                        \
        MFMA_BF16(afr[mi][0], bfr[(nq_)*2 + ni][0],                          \
                  acc[(mq_)*4 + mi][(nq_)*2 + ni], 0, 0, 0);                 \
    acc[(mq_)*4 + mi][(nq_)*2 + ni] =                                        \
        MFMA_BF16(afr[mi][1], bfr[(nq_)*2 + ni][1],                          \
                  acc[(mq_)*4 + mi][(nq_)*2 + ni], 0, 0, 0);                 \
  }                                                                          \
  __builtin_amdgcn_s_setprio(0);

#define BAR __builtin_amdgcn_s_barrier();
#define LGKM0 __asm__ __volatile__("s_waitcnt lgkmcnt(0)" ::: "memory");
#define VM(n) __asm__ __volatile__("s_waitcnt vmcnt(" #n ")" ::: "memory");

template <bool STORE_BF16>
__global__ __launch_bounds__(512, 2) void gemm256(
    const unsigned short* __restrict__ A, const unsigned short* __restrict__ B,
    void* __restrict__ Cout, size_t obuf_stride) {
  __shared__ short As[2][16384];  // 2 x 32 KB, 256 rows x 64 k
  __shared__ short Bs[2][16384];  // 2 x 32 KB

  const int t = threadIdx.x;
  const int lane = t & 63;
  const int quad = lane >> 4, l15 = lane & 15, l7 = l15 & 7;
  const int w = t >> 6, wm = w >> 2, wn = w & 3;

  // XCD-bijective block swizzle (both grids are multiples of 8)
  const int nwg = (int)gridDim.x;
  const int cpx = nwg >> 3;
  const int swz = ((int)blockIdx.x & 7) * cpx + ((int)blockIdx.x >> 3);
  const int bx = swz & 15, by = swz >> 4;
  const int row0 = bx * 256, col0g = by * 256;
  const int nb = col0g >> 11, col0 = col0g & 2047;

  // staging: thread t covers sub-row t>>3, 16B chunk t&7 (pre-inverse-swz src)
  const int rsub = t >> 3;
  const int cg8 = ((t & 7) ^ (rsub & 7)) << 3;
  const unsigned short* Ag = A + (size_t)(row0 + rsub) * GK + cg8;
  const unsigned short* Bg = B + (size_t)(col0g + rsub) * GK + cg8;
  const int loff = rsub * 128 + (t & 7) * 16;  // bytes within a half-tile

  // fragment read offsets (shorts); swizzled chunk = (kc*4+quad)^l7
  int aoff[4][2], boff[4][2];
#pragma unroll
  for (int mi = 0; mi < 4; ++mi)
#pragma unroll
    for (int kc = 0; kc < 2; ++kc)
      aoff[mi][kc] =
          (wm * 128 + mi * 16 + l15) * 64 + (((kc * 4 + quad) ^ l7) << 3);
#pragma unroll
  for (int ni = 0; ni < 4; ++ni)
#pragma unroll
    for (int kc = 0; kc < 2; ++kc)
      boff[ni][kc] =
          (wn * 64 + ni * 16 + l15) * 64 + (((kc * 4 + quad) ^ l7) << 3);

  f32x4 acc[8][4] = {};
  short8 afr[4][2], bfr[4][2];

  // ---- prologue: A(0),B(0) -> buf0; B(1) -> buf1 (12 loads) ----
  STAGE_A(0, 0, 0) STAGE_A(0, 1, 0)
  STAGE_B(0, 0, 0) STAGE_B(0, 1, 0)
  STAGE_B(1, 0, 1) STAGE_B(1, 1, 1)
  VM(4)  // oldest 8 landed = tile 0 complete; B(1) may remain in flight
  BAR

  for (int i = 0; i < 15; ++i) {
    const int t1 = 2 * i + 1;
    // ph1
    READ_A(0, 0) READ_B01(0)
    STAGE_A(1, 0, t1)
    BAR LGKM0
    PH_MFMA(0, 0)
    BAR
    // ph2
    READ_B23(0)
    STAGE_A(1, 1, t1)
    BAR LGKM0
    PH_MFMA(0, 1)
    BAR
    // ph3
    READ_A(0, 1)
    STAGE_B(0, 0, t1 + 1)
    BAR LGKM0
    PH_MFMA(1, 0)
    BAR
    // ph4
    STAGE_B(0, 1, t1 + 1)
    VM(4)  // A(2i+1) landed (outstanding = ph3/ph4 B stages)
    BAR
    PH_MFMA(1, 1)
    BAR
    // ph5
    READ_A(1, 0) READ_B01(1)
    STAGE_A(0, 0, t1 + 1)
    BAR LGKM0
    PH_MFMA(0, 0)
    BAR
    // ph6
    READ_B23(1)
    STAGE_A(0, 1, t1 + 1)
    BAR LGKM0
    PH_MFMA(0, 1)
    BAR
    // ph7
    READ_A(1, 1)
    STAGE_B(1, 0, t1 + 2)
    BAR LGKM0
    PH_MFMA(1, 0)
    BAR
    // ph8
    STAGE_B(1, 1, t1 + 2)
    VM(4)  // A(2i+2),B(2i+2) landed (outstanding = ph7/ph8 B stages)
    BAR
    PH_MFMA(1, 1)
    BAR
  }

  // ---- peeled last iteration (tiles 30 in buf0, 31 in buf1) ----
  {
    // ph1
    READ_A(0, 0) READ_B01(0)
    STAGE_A(1, 0, 31)
    BAR LGKM0
    PH_MFMA(0, 0)
    BAR
    // ph2
    READ_B23(0)
    STAGE_A(1, 1, 31)
    BAR LGKM0
    PH_MFMA(0, 1)
    BAR
    // ph3
    READ_A(0, 1)
    BAR LGKM0
    PH_MFMA(1, 0)
    BAR
    // ph4
    VM(0)  // drain: A(31) + B(31) all landed
    BAR
    PH_MFMA(1, 1)
    BAR
    // ph5
    READ_A(1, 0) READ_B01(1)
    BAR LGKM0
    PH_MFMA(0, 0)
    BAR
    // ph6
    READ_B23(1)
    BAR LGKM0
    PH_MFMA(0, 1)
    BAR
    // ph7
    READ_A(1, 1)
    BAR LGKM0
    PH_MFMA(1, 0)
    BAR
    // ph8
    PH_MFMA(1, 1)
  }

  // ---- epilogue ----
#pragma unroll
  for (int MI = 0; MI < 8; ++MI)
#pragma unroll
    for (int ni = 0; ni < 4; ++ni)
#pragma unroll
      for (int r = 0; r < 4; ++r) {
        int row = row0 + wm * 128 + MI * 16 + quad * 4 + r;
        int col = col0 + wn * 64 + ni * 16 + l15;
        if (STORE_BF16)
          ((unsigned short*)Cout)[nb * obuf_stride + (size_t)row * GN + col] =
              f2bf(acc[MI][ni][r]);
        else
          ((float*)Cout)[nb * obuf_stride + (size_t)row * GN + col] =
              acc[MI][ni][r];
      }
}

// ---------------------------------------------------------------------------
// V transpose: vb[b*S+s][d] -> vtb[(b*H + d>>7)*128 + (d&127)][s]
// ---------------------------------------------------------------------------
__global__ __launch_bounds__(256) void transpose_v(
    const unsigned short* __restrict__ vb, unsigned short* __restrict__ vtb) {
  __shared__ unsigned short tile[64][72];
  const int s0 = blockIdx.x * 64, d0 = blockIdx.y * 64, b = blockIdx.z;
  const int tid = threadIdx.x;
  const int c8 = tid & 7;
#pragma unroll
  for (int i = 0; i < 2; ++i) {
    int row = i * 32 + (tid >> 3);
    uint4 v = *(const uint4*)(vb + (size_t)(b * 2048 + s0 + row) * 2048 + d0 + c8 * 8);
    *(uint4*)&tile[row][c8 * 8] = v;
  }
  __syncthreads();
#pragma unroll
  for (int i = 0; i < 2; ++i) {
    int dr = i * 32 + (tid >> 3);
    short8 sv;
#pragma unroll
    for (int j = 0; j < 8; ++j) sv[j] = (short)tile[c8 * 8 + j][dr];
    int d = d0 + dr;
    int h = d >> 7, hd = d & 127;
    *(short8*)(vtb + ((size_t)(b * 16 + h) * 128 + hd) * 2048 + s0 + c8 * 8) = sv;
  }
}

// ---------------------------------------------------------------------------
// MFMA flash attention (R2 structure, measured 68 µs). Block = 64 q-rows of
// one (b,h); 4 waves, wave owns 16 q rows. Grid is FLAT 1024 with XCD-aware
// mapping: f = qt*32 + g (g = b*16+h), so all 32 q-tiles of a (b,h) group
// land on XCD g%8 (4 groups/XCD -> ~4MB K+V resident per XCD L2).
// ---------------------------------------------------------------------------
__global__ __launch_bounds__(256, 3) void attn_mfma(
    const unsigned short* __restrict__ Qm, const unsigned short* __restrict__ Km,
    const unsigned short* __restrict__ Vt, unsigned short* __restrict__ Om,
    const int* __restrict__ amask, const int* __restrict__ winp) {
  constexpr int S = 2048, D = 2048, HD = 128;
  const float SCALE = 0.08838834764831845f;  // 1/sqrt(128)

  __shared__ short Ks[64 * 128];   // K[key][d], chunk-swizzled (16 chunks/row)
  __shared__ short Vts[128 * 64];  // Vt[d][key], chunk-swizzled (8 chunks/row)
  __shared__ short Ps[4][16 * 64]; // per-wave P[q][key], swizzled (8 chunks/row)

  const int t = threadIdx.x, w = t >> 6, lane = t & 63;
  const int quad = lane >> 4, l15 = lane & 15;
  const int l7 = l15 & 7;
  // XCD-aware decode: f = qt*32 + (b*16+h)
  const int f = blockIdx.x;
  const int qt = f >> 5, g = f & 31;
  const int h = g & 15, b = g >> 4;
  const int qi0 = qt * 64;
  const int win = winp[0];

  // Q A-frags: A[m=l15][k=quad*8+j], 4 k-chunks of 32
  short8 qf[4];
  {
    const unsigned short* qp =
        Qm + (size_t)(b * S + qi0 + w * 16 + l15) * D + h * HD + quad * 8;
#pragma unroll
    for (int kc = 0; kc < 4; ++kc) qf[kc] = *(const short8*)(qp + kc * 32);
  }

  f32x4 o[8] = {};              // O[q=quad*4+r][d=ni2*16+l15]
  float m_r[4], l_r[4];
#pragma unroll
  for (int r = 0; r < 4; ++r) { m_r[r] = -1e30f; l_r[r] = 0.f; }

  int lowj = qi0 - win + 1;
  if (lowj < 0) lowj = 0;
  const int jt0 = lowj >> 6;

  const int krow = lane >> 4, kpos = lane & 15;  // K staging
  const int vrow = lane >> 3, vpos = lane & 7;   // Vt staging

  for (int jt = jt0; jt <= qt; ++jt) {
    const int j0 = jt * 64;
    __syncthreads();  // (A) prev tile's LDS reads done
#pragma unroll
    for (int ii = 0; ii < 4; ++ii) {
      int row = ii * 16 + w * 4 + krow;
      int c = kpos ^ (row & 7);
      async16(Km + (size_t)(b * S + j0 + row) * D + h * HD + c * 8,
              (char*)Ks + (ii * 16 + w * 4) * 256);
    }
#pragma unroll
    for (int ii = 0; ii < 4; ++ii) {
      int row = ii * 32 + w * 8 + vrow;
      int c = vpos ^ (row & 7);
      async16(Vt + ((size_t)(b * 16 + h) * 128 + row) * S + j0 + c * 8,
              (char*)Vts + (ii * 32 + w * 8) * 128);
    }
    __syncthreads();  // (B) K, Vt visible

    // ---- QK^T: S[q=quad*4+r][key=ni*16+l15] ----
    f32x4 sS[4];
#pragma unroll
    for (int ni = 0; ni < 4; ++ni) {
      f32x4 acc = {0.f, 0.f, 0.f, 0.f};
#pragma unroll
      for (int kc = 0; kc < 4; ++kc) {
        int pos = (kc * 4 + quad) ^ l7;
        short8 bk = *(const short8*)&Ks[(ni * 16 + l15) * 128 + pos * 8];
        acc = __builtin_amdgcn_mfma_f32_16x16x32_bf16(qf[kc], bk, acc, 0, 0, 0);
      }
      sS[ni] = acc;
    }

    // ---- mask + online softmax (quad-local rows) ----
    float sv[4][4];
    int amv[4];
#pragma unroll
    for (int ni = 0; ni < 4; ++ni) amv[ni] = amask[b * S + j0 + ni * 16 + l15];
#pragma unroll
    for (int ni = 0; ni < 4; ++ni)
#pragma unroll
      for (int r = 0; r < 4; ++r) {
        int gi = qi0 + w * 16 + quad * 4 + r;
        int gj = j0 + ni * 16 + l15;
        bool ok = (gj <= gi) && (gj >= gi - win + 1) && (amv[ni] != 0);
        sv[ni][r] = ok ? sS[ni][r] * SCALE : -1e30f;
      }
    float alpha[4], mnew[4];
#pragma unroll
    for (int r = 0; r < 4; ++r) {
      float mx = fmaxf(fmaxf(sv[0][r], sv[1][r]), fmaxf(sv[2][r], sv[3][r]));
      mx = fmaxf(mx, __shfl_xor(mx, 1));
      mx = fmaxf(mx, __shfl_xor(mx, 2));
      mx = fmaxf(mx, __shfl_xor(mx, 4));
      mx = fmaxf(mx, __shfl_xor(mx, 8));
      float mn = fmaxf(m_r[r], mx);
      alpha[r] = __expf(m_r[r] - mn);
      m_r[r] = mn;
      mnew[r] = mn;
    }
    float rs[4] = {0.f, 0.f, 0.f, 0.f};
#pragma unroll
    for (int ni = 0; ni < 4; ++ni)
#pragma unroll
      for (int r = 0; r < 4; ++r) {
        float p = (sv[ni][r] > -1e29f) ? __expf(sv[ni][r] - mnew[r]) : 0.f;
        sv[ni][r] = p;
        rs[r] += p;
      }
#pragma unroll
    for (int r = 0; r < 4; ++r) {
      float s = rs[r];
      s += __shfl_xor(s, 1);
      s += __shfl_xor(s, 2);
      s += __shfl_xor(s, 4);
      s += __shfl_xor(s, 8);
      l_r[r] = l_r[r] * alpha[r] + s;
    }
    // write P (bf16) into this wave's A-layout tile
#pragma unroll
    for (int ni = 0; ni < 4; ++ni)
#pragma unroll
      for (int r = 0; r < 4; ++r) {
        int row = quad * 4 + r;
        int col = ni * 16 + l15;
        int pos = (col >> 3) ^ (row & 7);
        Ps[w][row * 64 + pos * 8 + (col & 7)] = (short)f2bf(sv[ni][r]);
      }
    // rescale O
#pragma unroll
    for (int ni2 = 0; ni2 < 8; ++ni2)
#pragma unroll
      for (int r = 0; r < 4; ++r) o[ni2][r] *= alpha[r];

    // same-wave LDS write->read: drain lgkm, no barrier needed
    __asm__ __volatile__("s_waitcnt lgkmcnt(0)" ::: "memory");

    // ---- PV: O[q][d] += P[q][key] * Vt[d][key]^T ----
    short8 aP[2];
#pragma unroll
    for (int kc2 = 0; kc2 < 2; ++kc2) {
      int pos = (kc2 * 4 + quad) ^ l7;
      aP[kc2] = *(const short8*)&Ps[w][l15 * 64 + pos * 8];
    }
#pragma unroll
    for (int ni2 = 0; ni2 < 8; ++ni2) {
#pragma unroll
      for (int kc2 = 0; kc2 < 2; ++kc2) {
        int pos = (kc2 * 4 + quad) ^ l7;
        short8 bv = *(const short8*)&Vts[(ni2 * 16 + l15) * 64 + pos * 8];
        o[ni2] = __builtin_amdgcn_mfma_f32_16x16x32_bf16(aP[kc2], bv, o[ni2], 0, 0, 0);
      }
    }
  }

  // epilogue: O / l
  float inv[4];
#pragma unroll
  for (int r = 0; r < 4; ++r) inv[r] = 1.f / l_r[r];
#pragma unroll
  for (int ni2 = 0; ni2 < 8; ++ni2)
#pragma unroll
    for (int r = 0; r < 4; ++r) {
      int row = qi0 + w * 16 + quad * 4 + r;
      Om[(size_t)(b * S + row) * D + h * HD + ni2 * 16 + l15] =
          f2bf(o[ni2][r] * inv[r]);
    }
}

// ---------------------------------------------------------------------------
extern "C" void kernel_launch(void* const* d_in, const int* in_sizes, int n_in,
                              void* d_out, int out_size, void* d_ws,
                              size_t ws_size, hipStream_t stream) {
  (void)in_sizes; (void)n_in; (void)out_size; (void)ws_size;
  const float* x  = (const float*)d_in[0];
  const float* Wq = (const float*)d_in[1];
  const float* Wk = (const float*)d_in[2];
  const float* Wv = (const float*)d_in[3];
  const float* Wo = (const float*)d_in[4];
  const int* am   = (const int*)d_in[5];
  const int* win  = (const int*)d_in[6];
  // d_in[7] sink_tokens: unused (sink mask == causal per reference)

  char* ws = (char*)d_ws;  // needs >= 112 MB
  unsigned short* xb   = (unsigned short*)(ws + 0);
  unsigned short* vtb  = (unsigned short*)(ws + 0);  // aliases xb (dead then)
  unsigned short* wqkv = (unsigned short*)(ws + 16777216);  // [6144,2048]
  unsigned short* wob  = (unsigned short*)(ws + 41943040);
  unsigned short* qb   = (unsigned short*)(ws + 50331648);
  unsigned short* kb   = (unsigned short*)(ws + 67108864);  // qb + 8388608
  unsigned short* vb   = (unsigned short*)(ws + 83886080);  // qb + 2*8388608
  unsigned short* ab   = (unsigned short*)(ws + 100663296);

  cast_all<<<dim3(12288), dim3(256), 0, stream>>>(x, Wq, Wk, Wv, Wo, xb, wqkv, wob);

  // fused QKV: N_total = 6144 -> 16 x 24 = 384 blocks; col>>11 -> {qb,kb,vb}
  gemm256<true><<<dim3(384), dim3(512), 0, stream>>>(xb, wqkv, qb, 8388608);

  transpose_v<<<dim3(32, 32, 2), dim3(256), 0, stream>>>(vb, vtb);

  // flat 1024-block grid, XCD-swizzled (f = qt*32 + b*16 + h)
  attn_mfma<<<dim3(1024), dim3(256), 0, stream>>>(qb, kb, vtb, ab, am, win);

  // Wo GEMM: 16 x 8 = 128 blocks, fp32 out
  gemm256<false><<<dim3(128), dim3(512), 0, stream>>>(ab, wob, d_out, 0);
}

// Round 3
// 370.035 us; speedup vs baseline: 1.0444x; 1.0236x over previous
//
#include <hip/hip_runtime.h>
#include <stdint.h>

// ============================================================================
// R8: same 256x256 / 8-wave / 128KB geometry as R7, but the K-loop is
//     re-decomposed by (mq, kc) with ds_reads software-pipelined ONE PHASE
//     AHEAD, issued INSIDE the setprio/MFMA region so they overlap the MFMA
//     pipe (R7 post-mortem: reads and MFMA were serial -> inner 1107 TF).
//     One barrier per phase (was 2). 16 independent MFMAs per phase
//     (distinct accumulators). Frag regs unchanged (afA/afB/b0/b1 = 64 VGPR).
//     Phase p: stage(slot_p) -> [vmcnt(4) @P4/P8] -> barrier ->
//              setprio(1); reads(for p+1); 16 MFMA; setprio(0); lgkmcnt(0)
//     Stage slots (iter i: tile a=2i in buf0 P1-4, b=2i+1 in buf1 P5-8):
//       P1: A0(b)    P2: A1(b)    P3: B0(a+2)  P4: B1(a+2)+VM(4)
//       P5: A0(a+2)  P6: A1(a+2)  P7: B0(b+2)  P8: B1(b+2)+VM(4)
//     Liveness: each slot's region last-read >=2 phases earlier (barrier-
//     guaranteed); VM(4)@P4 forces tile b (A@P1,P2 + B@prev P7,P8) before
//     P4's read-ahead of b's frags; VM(4)@P8 forces tile a+2 symmetrically.
//     cast_all / transpose_v / attn_mfma unchanged.
// Shapes fixed: B=2, S=2048, D=2048, H=16, HD=128, window=512 (runtime-read).
// ws layout (bytes): xb@0 (16M, vtb aliases after QKV gemm) | wqkv@16M (25.2M)
//   wob@41.9M | qb@48M kb@64M vb@80M (16M apart = 8388608 elems) | ab@96M.
// ============================================================================

typedef __attribute__((ext_vector_type(8))) short short8;
typedef __attribute__((ext_vector_type(4))) float f32x4;

#define DEV static __device__ __forceinline__

DEV unsigned short f2bf(float f) {
  unsigned u = __builtin_bit_cast(unsigned, f);
  u += 0x7fffu + ((u >> 16) & 1u);  // RNE
  return (unsigned short)(u >> 16);
}

// async global->LDS, 16B/lane; LDS dest = wave-uniform base + lane*16
DEV void async16(const void* g, void* l) {
  __builtin_amdgcn_global_load_lds(
      (const __attribute__((address_space(1))) unsigned int*)g,
      (__attribute__((address_space(3))) unsigned int*)l, 16, 0, 0);
}

// ---------------------------------------------------------------------------
// Fused fp32 -> bf16 cast for x + Wq + Wk + Wv + Wo. 8 elems/thread.
// ---------------------------------------------------------------------------
__global__ __launch_bounds__(256) void cast_all(
    const float* __restrict__ x, const float* __restrict__ Wq,
    const float* __restrict__ Wk, const float* __restrict__ Wv,
    const float* __restrict__ Wo, unsigned short* __restrict__ xb,
    unsigned short* __restrict__ wqkv, unsigned short* __restrict__ wob) {
  const int bid = blockIdx.x;
  const float* src;
  unsigned short* dst;
  int i;
  if (bid < 4096) {
    src = x; dst = xb; i = bid * 256 + threadIdx.x;
  } else if (bid < 6144) {
    src = Wq; dst = wqkv; i = (bid - 4096) * 256 + threadIdx.x;
  } else if (bid < 8192) {
    src = Wk; dst = wqkv + 4194304; i = (bid - 6144) * 256 + threadIdx.x;
  } else if (bid < 10240) {
    src = Wv; dst = wqkv + 8388608; i = (bid - 8192) * 256 + threadIdx.x;
  } else {
    src = Wo; dst = wob; i = (bid - 10240) * 256 + threadIdx.x;
  }
  const float4* s4 = (const float4*)src;
  float4 a = s4[2 * (size_t)i], b = s4[2 * (size_t)i + 1];
  short8 o;
  o[0] = (short)f2bf(a.x); o[1] = (short)f2bf(a.y);
  o[2] = (short)f2bf(a.z); o[3] = (short)f2bf(a.w);
  o[4] = (short)f2bf(b.x); o[5] = (short)f2bf(b.y);
  o[6] = (short)f2bf(b.z); o[7] = (short)f2bf(b.w);
  *(short8*)(dst + 8 * (size_t)i) = o;
}

// ---------------------------------------------------------------------------
// C = A[M,K] * B[NT,K]^T, k-contiguous bf16. M=4096, K=2048 fixed.
// BM=BN=256, BK=64; 512 threads = 8 waves (2M x 4N), wave tile 128x64.
// ---------------------------------------------------------------------------
constexpr int GK = 2048, GN = 2048;

#define MFMA_BF16 __builtin_amdgcn_mfma_f32_16x16x32_bf16

#define STAGE_A(buf, h, kt)                                                  \
  {                                                                          \
    const unsigned short* g_ = Ag + (size_t)((h) * 128) * GK + (kt) * 64;    \
    char* d_ = (char*)As[buf] + (h) * 16384 + loff;                          \
    async16(g_, d_);                                                         \
    async16(g_ + (size_t)64 * GK, d_ + 8192);                                \
  }
#define STAGE_B(buf, h, kt)                                                  \
  {                                                                          \
    const unsigned short* g_ = Bg + (size_t)((h) * 128) * GK + (kt) * 64;    \
    char* d_ = (char*)Bs[buf] + (h) * 16384 + loff;                          \
    async16(g_, d_);                                                         \
    async16(g_ + (size_t)64 * GK, d_ + 8192);                                \
  }

// read 4 A-frags (one mq, one kc) / 4 B-frags (one kc)
#define READ_AF(dst, buf, mq, kc)                                            \
  _Pragma("unroll") for (int mi = 0; mi < 4; ++mi) dst[mi] =                 \
      *(const short8*)(As[buf] + aoffk[kc] + (mq)*4096 + mi * 1024);
#define READ_BF(dst, buf, kc)                                                \
  _Pragma("unroll") for (int ni = 0; ni < 4; ++ni) dst[ni] =                 \
      *(const short8*)(Bs[buf] + boffk[kc] + ni * 1024);

// 16 independent MFMAs: acc[mq*4+mi][ni] += A_[mi] x B_[ni]
#define MFMA16(mq, A_, B_)                                                   \
  _Pragma("unroll") for (int mi = 0; mi < 4; ++mi)                           \
      _Pragma("unroll") for (int ni = 0; ni < 4; ++ni)                       \
      acc[(mq)*4 + mi][ni] =                                                 \
      MFMA_BF16(A_[mi], B_[ni], acc[(mq)*4 + mi][ni], 0, 0, 0);

#define MEMF __asm__ __volatile__("" ::: "memory");
#define BARR { MEMF __builtin_amdgcn_s_barrier(); MEMF }
#define SP1 __builtin_amdgcn_s_setprio(1);
#define SP0 __builtin_amdgcn_s_setprio(0);
#define LGKM0 __asm__ __volatile__("s_waitcnt lgkmcnt(0)" ::: "memory");
#define VM(n) __asm__ __volatile__("s_waitcnt vmcnt(" #n ")" ::: "memory");

template <bool STORE_BF16>
__global__ __launch_bounds__(512, 2) void gemm256(
    const unsigned short* __restrict__ A, const unsigned short* __restrict__ B,
    void* __restrict__ Cout, size_t obuf_stride) {
  __shared__ short As[2][16384];  // 2 x 32 KB, 256 rows x 64 k
  __shared__ short Bs[2][16384];  // 2 x 32 KB

  const int t = threadIdx.x;
  const int lane = t & 63;
  const int quad = lane >> 4, l15 = lane & 15, l7 = l15 & 7;
  const int w = t >> 6, wm = w >> 2, wn = w & 3;

  // XCD-bijective block swizzle (both grids are multiples of 8)
  const int nwg = (int)gridDim.x;
  const int cpx = nwg >> 3;
  const int swz = ((int)blockIdx.x & 7) * cpx + ((int)blockIdx.x >> 3);
  const int bx = swz & 15, by = swz >> 4;
  const int row0 = bx * 256, col0g = by * 256;
  const int nb = col0g >> 11, col0 = col0g & 2047;

  // staging: thread t covers sub-row t>>3, 16B chunk t&7 (pre-inverse-swz src)
  const int rsub = t >> 3;
  const int cg8 = ((t & 7) ^ (rsub & 7)) << 3;
  const unsigned short* Ag = A + (size_t)(row0 + rsub) * GK + cg8;
  const unsigned short* Bg = B + (size_t)(col0g + rsub) * GK + cg8;
  const int loff = rsub * 128 + (t & 7) * 16;  // bytes within a half-tile

  // fragment read bases per kc (elements); swizzled chunk = (kc*4+quad)^l7
  int aoffk[2], boffk[2];
#pragma unroll
  for (int kc = 0; kc < 2; ++kc) {
    int swzc = (((kc * 4 + quad) ^ l7) << 3);
    aoffk[kc] = wm * 8192 + l15 * 64 + swzc;
    boffk[kc] = wn * 4096 + l15 * 64 + swzc;
  }

  f32x4 acc[8][4] = {};
  short8 afA[4], afB[4], b0[4], b1[4];

  // ---- prologue: tile0 (A+B) -> buf0, tile1 B -> buf1 (12 loads) ----
  STAGE_A(0, 0, 0) STAGE_A(0, 1, 0)
  STAGE_B(0, 0, 0) STAGE_B(0, 1, 0)
  STAGE_B(1, 0, 1) STAGE_B(1, 1, 1)
  VM(4)  // forces tile0's 8 loads; tile1's B may stay in flight
  BARR
  READ_AF(afA, 0, 0, 0) READ_BF(b0, 0, 0)
  LGKM0

#pragma unroll 1
  for (int i = 0; i < 15; ++i) {
    const int t1 = 2 * i + 1;
    // P1: (a, mq0, kc0)
    STAGE_A(1, 0, t1)
    BARR
    SP1 READ_AF(afB, 0, 0, 1) READ_BF(b1, 0, 1) MFMA16(0, afA, b0) SP0 LGKM0
    // P2: (a, mq0, kc1)
    STAGE_A(1, 1, t1)
    BARR
    SP1 READ_AF(afA, 0, 1, 0) MFMA16(0, afB, b1) SP0 LGKM0
    // P3: (a, mq1, kc0)
    STAGE_B(0, 0, t1 + 1)
    BARR
    SP1 READ_AF(afB, 0, 1, 1) MFMA16(1, afA, b0) SP0 LGKM0
    // P4: (a, mq1, kc1); checkpoint -> tile b fully landed
    STAGE_B(0, 1, t1 + 1)
    VM(4)
    BARR
    SP1 READ_AF(afA, 1, 0, 0) READ_BF(b0, 1, 0) MFMA16(1, afB, b1) SP0 LGKM0
    // P5: (b, mq0, kc0)
    STAGE_A(0, 0, t1 + 1)
    BARR
    SP1 READ_AF(afB, 1, 0, 1) READ_BF(b1, 1, 1) MFMA16(0, afA, b0) SP0 LGKM0
    // P6: (b, mq0, kc1)
    STAGE_A(0, 1, t1 + 1)
    BARR
    SP1 READ_AF(afA, 1, 1, 0) MFMA16(0, afB, b1) SP0 LGKM0
    // P7: (b, mq1, kc0)
    STAGE_B(1, 0, t1 + 2)
    BARR
    SP1 READ_AF(afB, 1, 1, 1) MFMA16(1, afA, b0) SP0 LGKM0
    // P8: (b, mq1, kc1); checkpoint -> tile a+2 fully landed
    STAGE_B(1, 1, t1 + 2)
    VM(4)
    BARR
    SP1 READ_AF(afA, 0, 0, 0) READ_BF(b0, 0, 0) MFMA16(1, afB, b1) SP0 LGKM0
  }

  // ---- peeled last iteration (tiles 30 in buf0, 31 in buf1) ----
  {
    // P1
    STAGE_A(1, 0, 31)
    BARR
    SP1 READ_AF(afB, 0, 0, 1) READ_BF(b1, 0, 1) MFMA16(0, afA, b0) SP0 LGKM0
    // P2
    STAGE_A(1, 1, 31)
    BARR
    SP1 READ_AF(afA, 0, 1, 0) MFMA16(0, afB, b1) SP0 LGKM0
    // P3
    BARR
    SP1 READ_AF(afB, 0, 1, 1) MFMA16(1, afA, b0) SP0 LGKM0
    // P4: drain -> tile 31 landed
    VM(0)
    BARR
    SP1 READ_AF(afA, 1, 0, 0) READ_BF(b0, 1, 0) MFMA16(1, afB, b1) SP0 LGKM0
    // P5
    BARR
    SP1 READ_AF(afB, 1, 0, 1) READ_BF(b1, 1, 1) MFMA16(0, afA, b0) SP0 LGKM0
    // P6
    BARR
    SP1 READ_AF(afA, 1, 1, 0) MFMA16(0, afB, b1) SP0 LGKM0
    // P7
    BARR
    SP1 READ_AF(afB, 1, 1, 1) MFMA16(1, afA, b0) SP0 LGKM0
    // P8
    BARR
    SP1 MFMA16(1, afB, b1) SP0
  }

  // ---- epilogue ----
#pragma unroll
  for (int MI = 0; MI < 8; ++MI)
#pragma unroll
    for (int ni = 0; ni < 4; ++ni)
#pragma unroll
      for (int r = 0; r < 4; ++r) {
        int row = row0 + wm * 128 + MI * 16 + quad * 4 + r;
        int col = col0 + wn * 64 + ni * 16 + l15;
        if (STORE_BF16)
          ((unsigned short*)Cout)[nb * obuf_stride + (size_t)row * GN + col] =
              f2bf(acc[MI][ni][r]);
        else
          ((float*)Cout)[nb * obuf_stride + (size_t)row * GN + col] =
              acc[MI][ni][r];
      }
}

// ---------------------------------------------------------------------------
// V transpose: vb[b*S+s][d] -> vtb[(b*H + d>>7)*128 + (d&127)][s]
// ---------------------------------------------------------------------------
__global__ __launch_bounds__(256) void transpose_v(
    const unsigned short* __restrict__ vb, unsigned short* __restrict__ vtb) {
  __shared__ unsigned short tile[64][72];
  const int s0 = blockIdx.x * 64, d0 = blockIdx.y * 64, b = blockIdx.z;
  const int tid = threadIdx.x;
  const int c8 = tid & 7;
#pragma unroll
  for (int i = 0; i < 2; ++i) {
    int row = i * 32 + (tid >> 3);
    uint4 v = *(const uint4*)(vb + (size_t)(b * 2048 + s0 + row) * 2048 + d0 + c8 * 8);
    *(uint4*)&tile[row][c8 * 8] = v;
  }
  __syncthreads();
#pragma unroll
  for (int i = 0; i < 2; ++i) {
    int dr = i * 32 + (tid >> 3);
    short8 sv;
#pragma unroll
    for (int j = 0; j < 8; ++j) sv[j] = (short)tile[c8 * 8 + j][dr];
    int d = d0 + dr;
    int h = d >> 7, hd = d & 127;
    *(short8*)(vtb + ((size_t)(b * 16 + h) * 128 + hd) * 2048 + s0 + c8 * 8) = sv;
  }
}

// ---------------------------------------------------------------------------
// MFMA flash attention (R2 structure, measured 68 µs). Block = 64 q-rows of
// one (b,h); 4 waves, wave owns 16 q rows. Grid is FLAT 1024 with XCD-aware
// mapping: f = qt*32 + g (g = b*16+h), so all 32 q-tiles of a (b,h) group
// land on XCD g%8 (4 groups/XCD -> ~4MB K+V resident per XCD L2).
// ---------------------------------------------------------------------------
__global__ __launch_bounds__(256, 3) void attn_mfma(
    const unsigned short* __restrict__ Qm, const unsigned short* __restrict__ Km,
    const unsigned short* __restrict__ Vt, unsigned short* __restrict__ Om,
    const int* __restrict__ amask, const int* __restrict__ winp) {
  constexpr int S = 2048, D = 2048, HD = 128;
  const float SCALE = 0.08838834764831845f;  // 1/sqrt(128)

  __shared__ short Ks[64 * 128];   // K[key][d], chunk-swizzled (16 chunks/row)
  __shared__ short Vts[128 * 64];  // Vt[d][key], chunk-swizzled (8 chunks/row)
  __shared__ short Ps[4][16 * 64]; // per-wave P[q][key], swizzled (8 chunks/row)

  const int t = threadIdx.x, w = t >> 6, lane = t & 63;
  const int quad = lane >> 4, l15 = lane & 15;
  const int l7 = l15 & 7;
  // XCD-aware decode: f = qt*32 + (b*16+h)
  const int f = blockIdx.x;
  const int qt = f >> 5, g = f & 31;
  const int h = g & 15, b = g >> 4;
  const int qi0 = qt * 64;
  const int win = winp[0];

  // Q A-frags: A[m=l15][k=quad*8+j], 4 k-chunks of 32
  short8 qf[4];
  {
    const unsigned short* qp =
        Qm + (size_t)(b * S + qi0 + w * 16 + l15) * D + h * HD + quad * 8;
#pragma unroll
    for (int kc = 0; kc < 4; ++kc) qf[kc] = *(const short8*)(qp + kc * 32);
  }

  f32x4 o[8] = {};              // O[q=quad*4+r][d=ni2*16+l15]
  float m_r[4], l_r[4];
#pragma unroll
  for (int r = 0; r < 4; ++r) { m_r[r] = -1e30f; l_r[r] = 0.f; }

  int lowj = qi0 - win + 1;
  if (lowj < 0) lowj = 0;
  const int jt0 = lowj >> 6;

  const int krow = lane >> 4, kpos = lane & 15;  // K staging
  const int vrow = lane >> 3, vpos = lane & 7;   // Vt staging

  for (int jt = jt0; jt <= qt; ++jt) {
    const int j0 = jt * 64;
    __syncthreads();  // (A) prev tile's LDS reads done
#pragma unroll
    for (int ii = 0; ii < 4; ++ii) {
      int row = ii * 16 + w * 4 + krow;
      int c = kpos ^ (row & 7);
      async16(Km + (size_t)(b * S + j0 + row) * D + h * HD + c * 8,
              (char*)Ks + (ii * 16 + w * 4) * 256);
    }
#pragma unroll
    for (int ii = 0; ii < 4; ++ii) {
      int row = ii * 32 + w * 8 + vrow;
      int c = vpos ^ (row & 7);
      async16(Vt + ((size_t)(b * 16 + h) * 128 + row) * S + j0 + c * 8,
              (char*)Vts + (ii * 32 + w * 8) * 128);
    }
    __syncthreads();  // (B) K, Vt visible

    // ---- QK^T: S[q=quad*4+r][key=ni*16+l15] ----
    f32x4 sS[4];
#pragma unroll
    for (int ni = 0; ni < 4; ++ni) {
      f32x4 acc = {0.f, 0.f, 0.f, 0.f};
#pragma unroll
      for (int kc = 0; kc < 4; ++kc) {
        int pos = (kc * 4 + quad) ^ l7;
        short8 bk = *(const short8*)&Ks[(ni * 16 + l15) * 128 + pos * 8];
        acc = __builtin_amdgcn_mfma_f32_16x16x32_bf16(qf[kc], bk, acc, 0, 0, 0);
      }
      sS[ni] = acc;
    }

    // ---- mask + online softmax (quad-local rows) ----
    float sv[4][4];
    int amv[4];
#pragma unroll
    for (int ni = 0; ni < 4; ++ni) amv[ni] = amask[b * S + j0 + ni * 16 + l15];
#pragma unroll
    for (int ni = 0; ni < 4; ++ni)
#pragma unroll
      for (int r = 0; r < 4; ++r) {
        int gi = qi0 + w * 16 + quad * 4 + r;
        int gj = j0 + ni * 16 + l15;
        bool ok = (gj <= gi) && (gj >= gi - win + 1) && (amv[ni] != 0);
        sv[ni][r] = ok ? sS[ni][r] * SCALE : -1e30f;
      }
    float alpha[4], mnew[4];
#pragma unroll
    for (int r = 0; r < 4; ++r) {
      float mx = fmaxf(fmaxf(sv[0][r], sv[1][r]), fmaxf(sv[2][r], sv[3][r]));
      mx = fmaxf(mx, __shfl_xor(mx, 1));
      mx = fmaxf(mx, __shfl_xor(mx, 2));
      mx = fmaxf(mx, __shfl_xor(mx, 4));
      mx = fmaxf(mx, __shfl_xor(mx, 8));
      float mn = fmaxf(m_r[r], mx);
      alpha[r] = __expf(m_r[r] - mn);
      m_r[r] = mn;
      mnew[r] = mn;
    }
    float rs[4] = {0.f, 0.f, 0.f, 0.f};
#pragma unroll
    for (int ni = 0; ni < 4; ++ni)
#pragma unroll
      for (int r = 0; r < 4; ++r) {
        float p = (sv[ni][r] > -1e29f) ? __expf(sv[ni][r] - mnew[r]) : 0.f;
        sv[ni][r] = p;
        rs[r] += p;
      }
#pragma unroll
    for (int r = 0; r < 4; ++r) {
      float s = rs[r];
      s += __shfl_xor(s, 1);
      s += __shfl_xor(s, 2);
      s += __shfl_xor(s, 4);
      s += __shfl_xor(s, 8);
      l_r[r] = l_r[r] * alpha[r] + s;
    }
    // write P (bf16) into this wave's A-layout tile
#pragma unroll
    for (int ni = 0; ni < 4; ++ni)
#pragma unroll
      for (int r = 0; r < 4; ++r) {
        int row = quad * 4 + r;
        int col = ni * 16 + l15;
        int pos = (col >> 3) ^ (row & 7);
        Ps[w][row * 64 + pos * 8 + (col & 7)] = (short)f2bf(sv[ni][r]);
      }
    // rescale O
#pragma unroll
    for (int ni2 = 0; ni2 < 8; ++ni2)
#pragma unroll
      for (int r = 0; r < 4; ++r) o[ni2][r] *= alpha[r];

    // same-wave LDS write->read: drain lgkm, no barrier needed
    __asm__ __volatile__("s_waitcnt lgkmcnt(0)" ::: "memory");

    // ---- PV: O[q][d] += P[q][key] * Vt[d][key]^T ----
    short8 aP[2];
#pragma unroll
    for (int kc2 = 0; kc2 < 2; ++kc2) {
      int pos = (kc2 * 4 + quad) ^ l7;
      aP[kc2] = *(const short8*)&Ps[w][l15 * 64 + pos * 8];
    }
#pragma unroll
    for (int ni2 = 0; ni2 < 8; ++ni2) {
#pragma unroll
      for (int kc2 = 0; kc2 < 2; ++kc2) {
        int pos = (kc2 * 4 + quad) ^ l7;
        short8 bv = *(const short8*)&Vts[(ni2 * 16 + l15) * 64 + pos * 8];
        o[ni2] = __builtin_amdgcn_mfma_f32_16x16x32_bf16(aP[kc2], bv, o[ni2], 0, 0, 0);
      }
    }
  }

  // epilogue: O / l
  float inv[4];
#pragma unroll
  for (int r = 0; r < 4; ++r) inv[r] = 1.f / l_r[r];
#pragma unroll
  for (int ni2 = 0; ni2 < 8; ++ni2)
#pragma unroll
    for (int r = 0; r < 4; ++r) {
      int row = qi0 + w * 16 + quad * 4 + r;
      Om[(size_t)(b * S + row) * D + h * HD + ni2 * 16 + l15] =
          f2bf(o[ni2][r] * inv[r]);
    }
}

// ---------------------------------------------------------------------------
extern "C" void kernel_launch(void* const* d_in, const int* in_sizes, int n_in,
                              void* d_out, int out_size, void* d_ws,
                              size_t ws_size, hipStream_t stream) {
  (void)in_sizes; (void)n_in; (void)out_size; (void)ws_size;
  const float* x  = (const float*)d_in[0];
  const float* Wq = (const float*)d_in[1];
  const float* Wk = (const float*)d_in[2];
  const float* Wv = (const float*)d_in[3];
  const float* Wo = (const float*)d_in[4];
  const int* am   = (const int*)d_in[5];
  const int* win  = (const int*)d_in[6];
  // d_in[7] sink_tokens: unused (sink mask == causal per reference)

  char* ws = (char*)d_ws;  // needs >= 112 MB
  unsigned short* xb   = (unsigned short*)(ws + 0);
  unsigned short* vtb  = (unsigned short*)(ws + 0);  // aliases xb (dead then)
  unsigned short* wqkv = (unsigned short*)(ws + 16777216);  // [6144,2048]
  unsigned short* wob  = (unsigned short*)(ws + 41943040);
  unsigned short* qb   = (unsigned short*)(ws + 50331648);
  unsigned short* kb   = (unsigned short*)(ws + 67108864);  // qb + 8388608
  unsigned short* vb   = (unsigned short*)(ws + 83886080);  // qb + 2*8388608
  unsigned short* ab   = (unsigned short*)(ws + 100663296);

  cast_all<<<dim3(12288), dim3(256), 0, stream>>>(x, Wq, Wk, Wv, Wo, xb, wqkv, wob);

  // fused QKV: N_total = 6144 -> 16 x 24 = 384 blocks; col>>11 -> {qb,kb,vb}
  gemm256<true><<<dim3(384), dim3(512), 0, stream>>>(xb, wqkv, qb, 8388608);

  transpose_v<<<dim3(32, 32, 2), dim3(256), 0, stream>>>(vb, vtb);

  // flat 1024-block grid, XCD-swizzled (f = qt*32 + b*16 + h)
  attn_mfma<<<dim3(1024), dim3(256), 0, stream>>>(qb, kb, vtb, ab, am, win);

  // Wo GEMM: 16 x 8 = 128 blocks, fp32 out
  gemm256<false><<<dim3(128), dim3(512), 0, stream>>>(ab, wob, d_out, 0);
}